// Round 1
// baseline (93.392 us; speedup 1.0000x reference)
//
#include <hip/hip_runtime.h>

// KernelRepeatLinear: out[b,e,j] = bias[j] + sum_k weight[k,j] * y[b, e+k-7, j]
// where y[b,e',j] = sum_{i<=j} x[b,e',i] * dv^(j-i)  (decayed prefix scan over features)
// dv = clip(decay_value[1], 0.9, 1.0). y rows with e' < 0 are zero (causal padding).

#define B_    8
#define E_    2048
#define DIM_  512
#define K_    8
#define TILE_E 25
#define NROWS  (TILE_E + K_ - 1)   // 32 -> LDS 32*512*4 = 64 KB, 2 blocks/CU

__global__ __launch_bounds__(256) void krl_fused(
    const float* __restrict__ x,
    const float* __restrict__ weight,
    const float* __restrict__ bias,
    const float* __restrict__ decay,
    float* __restrict__ out)
{
    __shared__ float yls[NROWS][DIM_];

    const int tile = blockIdx.x;
    const int b    = blockIdx.y;
    const int e0   = tile * TILE_E;
    const int nout = min(TILE_E, E_ - e0);
    const int nscan = nout + K_ - 1;

    const int t    = threadIdx.x;
    const int lane = t & 63;
    const int wave = t >> 6;

    float dv = decay[1];
    dv = fminf(fmaxf(dv, 0.9f), 1.0f);
    const float dv2 = dv * dv;
    const float dv4 = dv2 * dv2;
    const float dv8 = dv4 * dv4;

    // ---- Phase 1: decayed prefix scan along features, one row per wave ----
    // LDS row r corresponds to e_global = e0 - 7 + r.
    for (int r = wave; r < nscan; r += 4) {
        const int eg = e0 - (K_ - 1) + r;
        float tl[8];
        if (eg >= 0) {
            const float4* xp = (const float4*)(x + ((size_t)b * E_ + eg) * DIM_ + lane * 8);
            const float4 a0 = xp[0];
            const float4 a1 = xp[1];
            const float xv[8] = {a0.x, a0.y, a0.z, a0.w, a1.x, a1.y, a1.z, a1.w};
            // lane-local scan over 8 contiguous elements
            tl[0] = xv[0];
            #pragma unroll
            for (int m = 1; m < 8; ++m) tl[m] = fmaf(dv, tl[m - 1], xv[m]);
            // cross-lane recurrence Y_l = T_l + dv^8 * Y_{l-1} via Kogge-Stone
            float v  = tl[7];
            float ap = dv8;
            #pragma unroll
            for (int off = 1; off < 64; off <<= 1) {
                float up = __shfl_up(v, off, 64);
                if (lane >= off) v = fmaf(ap, up, v);
                ap *= ap;
            }
            float carry = __shfl_up(v, 1, 64);   // y[8*lane - 1]
            if (lane == 0) carry = 0.f;
            float dp = dv;
            #pragma unroll
            for (int m = 0; m < 8; ++m) { tl[m] = fmaf(dp, carry, tl[m]); dp *= dv; }
        } else {
            #pragma unroll
            for (int m = 0; m < 8; ++m) tl[m] = 0.f;
        }
        float4* yp = (float4*)(&yls[r][lane * 8]);
        yp[0] = make_float4(tl[0], tl[1], tl[2], tl[3]);
        yp[1] = make_float4(tl[4], tl[5], tl[6], tl[7]);
    }
    __syncthreads();

    // ---- Phase 2: depthwise causal conv (K=8) along E, per feature ----
    // 128 threads cover 512 features as float4; 2 groups interleave output rows.
    const int g  = t >> 7;          // row-group 0/1
    const int jf = (t & 127) * 4;   // feature base

    float4 w[K_];
    #pragma unroll
    for (int k = 0; k < K_; ++k) w[k] = *(const float4*)(weight + k * DIM_ + jf);
    const float4 bi = *(const float4*)(bias + jf);

    for (int te = g; te < nout; te += 2) {
        float4 acc = bi;
        #pragma unroll
        for (int k = 0; k < K_; ++k) {
            const float4 yv = *(const float4*)(&yls[te + k][jf]);
            acc.x = fmaf(w[k].x, yv.x, acc.x);
            acc.y = fmaf(w[k].y, yv.y, acc.y);
            acc.z = fmaf(w[k].z, yv.z, acc.z);
            acc.w = fmaf(w[k].w, yv.w, acc.w);
        }
        *(float4*)(out + ((size_t)b * E_ + e0 + te) * DIM_ + jf) = acc;
    }
}

extern "C" void kernel_launch(void* const* d_in, const int* in_sizes, int n_in,
                              void* d_out, int out_size, void* d_ws, size_t ws_size,
                              hipStream_t stream) {
    const float* x      = (const float*)d_in[0];
    const float* weight = (const float*)d_in[1];
    const float* bias   = (const float*)d_in[2];
    const float* decay  = (const float*)d_in[3];
    float* out = (float*)d_out;

    dim3 grid((E_ + TILE_E - 1) / TILE_E, B_);  // 82 x 8 = 656 blocks
    dim3 block(256);
    krl_fused<<<grid, block, 0, stream>>>(x, weight, bias, decay, out);
}